// Round 1
// baseline (1361.220 us; speedup 1.0000x reference)
//
#include <hip/hip_runtime.h>
#include <hip/hip_bf16.h>
#include <cstdint>
#include <cstddef>

#define AS1 __attribute__((address_space(1)))
#define AS3 __attribute__((address_space(3)))

typedef __hip_bfloat16 bf16;
typedef float f32x4 __attribute__((ext_vector_type(4)));
typedef short bf16x8 __attribute__((ext_vector_type(8)));

#define B_     4
#define T_     2048
#define D_     1024
#define E_     8
#define H_     4096
#define NTOK   8192
#define CAP    1280
#define VOCAB_ 256

// ---- workspace layout (bytes) ----
static constexpr size_t OFF_P     = 0;                 // 256*1024*4   = 1 MB
static constexpr size_t OFF_G     = 1048576;           // 1 MB
static constexpr size_t OFF_Y     = 2097152;           // 8192*1024*4  = 32 MB
static constexpr size_t OFF_TOP   = 35651584;          // 8192*4
static constexpr size_t OFF_GATE  = 35684352;          // 8192*4
static constexpr size_t OFF_ENT   = 35717120;          // 8192*4
static constexpr size_t OFF_CNT   = 35749888;          // 8*4 (pad 256)
static constexpr size_t OFF_CKEPT = 35750144;          // 8*4 (pad 256)
static constexpr size_t OFF_SLOT  = 35750400;          // 10240*4
static constexpr size_t OFF_XE    = 35791360;          // 10240*1024*2 = 20 MB
static constexpr size_t OFF_HE    = 56762880;          // 10240*4096*2 = 80 MB
static constexpr size_t OFF_WT    = 140648960;         // 64 MB (W1t then W2t)
static constexpr size_t OFF_WHT   = 207757824;         // 256*1024*2
static constexpr size_t OFF_OUTB  = 208282112;         // 8192*1024*2  = 16 MB

// d_out layout (floats)
#define LOGITS_OFF 0
#define NS_OFF     2097152
#define ENT_OFF    2101248
#define CNT_OFF    2101249

__device__ __forceinline__ void gll16(const void* g, void* l) {
  __builtin_amdgcn_global_load_lds((AS1 const void*)g, (AS3 void*)l, 16, 0, 0);
}
__device__ __forceinline__ unsigned short f2bu(float f) {
  bf16 h = __float2bfloat16(f);
  return __builtin_bit_cast(unsigned short, h);
}

// ---------------- embedding projection tables ----------------
// P = emb@Wp+bp, G = sigmoid(emb@Wg+bg); [256][1024] each.
__global__ __launch_bounds__(256) void slv_embproj(
    const float* __restrict__ emb, const float* __restrict__ Wp, const float* __restrict__ bp,
    const float* __restrict__ Wg, const float* __restrict__ bg,
    float* __restrict__ P, float* __restrict__ G) {
  int c  = blockIdx.x * 256 + threadIdx.x;   // 0..1023
  int r0 = blockIdx.y * 16;                  // 16 vocab rows per block
  float accP[16], accG[16];
  #pragma unroll
  for (int r = 0; r < 16; ++r) { accP[r] = 0.f; accG[r] = 0.f; }
  for (int k = 0; k < D_; ++k) {
    float wp = Wp[k * D_ + c], wg = Wg[k * D_ + c];
    #pragma unroll
    for (int r = 0; r < 16; ++r) {
      float e = emb[(r0 + r) * D_ + k];
      accP[r] = fmaf(e, wp, accP[r]);
      accG[r] = fmaf(e, wg, accG[r]);
    }
  }
  float bpc = bp[c], bgc = bg[c];
  #pragma unroll
  for (int r = 0; r < 16; ++r) {
    P[(r0 + r) * D_ + c] = accP[r] + bpc;
    G[(r0 + r) * D_ + c] = 1.f / (1.f + expf(-(accG[r] + bgc)));
  }
}

// ---------------- SSM scan ----------------
// 4096 channels (b,d), each serial over T. y[b,t,d] = G*s ; next_state -> d_out.
__global__ __launch_bounds__(256) void slv_scan(
    const int* __restrict__ bytes, const float* __restrict__ P, const float* __restrict__ G,
    float* __restrict__ y, float* __restrict__ ns) {
  int b = blockIdx.x >> 2;
  int d = (blockIdx.x & 3) * 256 + threadIdx.x;
  __shared__ int bl[T_];
  for (int i = threadIdx.x; i < T_; i += 256) bl[i] = bytes[b * T_ + i];
  __syncthreads();
  float s = 0.f;
  for (int t = 0; t < T_; ++t) {
    int by = bl[t];
    float p = P[by * D_ + d];
    float g = G[by * D_ + d];
    s = tanhf(p + s);
    y[((size_t)(b * T_ + t)) * D_ + d] = g * s;
  }
  ns[b * D_ + d] = s;
}

// ---------------- router ----------------
// one wave per token: logits = y@Wr+br, softmax, argmax(first-max), gate, entropy.
__global__ __launch_bounds__(256) void slv_router(
    const float* __restrict__ y, const float* __restrict__ Wr, const float* __restrict__ br,
    int* __restrict__ top, float* __restrict__ gate, float* __restrict__ entTok,
    int* __restrict__ countsInt) {
  int wave = threadIdx.x >> 6, lane = threadIdx.x & 63;
  int tok = blockIdx.x * 4 + wave;
  const float* yr = y + (size_t)tok * D_;
  float acc[E_];
  #pragma unroll
  for (int e = 0; e < E_; ++e) acc[e] = 0.f;
  for (int i = 0; i < 16; ++i) {
    int d = i * 64 + lane;
    float v = yr[d];
    const float4* w = (const float4*)(Wr + d * E_);
    float4 w0 = w[0], w1 = w[1];
    acc[0] = fmaf(v, w0.x, acc[0]); acc[1] = fmaf(v, w0.y, acc[1]);
    acc[2] = fmaf(v, w0.z, acc[2]); acc[3] = fmaf(v, w0.w, acc[3]);
    acc[4] = fmaf(v, w1.x, acc[4]); acc[5] = fmaf(v, w1.y, acc[5]);
    acc[6] = fmaf(v, w1.z, acc[6]); acc[7] = fmaf(v, w1.w, acc[7]);
  }
  #pragma unroll
  for (int off = 32; off; off >>= 1)
    #pragma unroll
    for (int e = 0; e < E_; ++e) acc[e] += __shfl_xor(acc[e], off);
  if (lane == 0) {
    float l[E_], p[E_];
    float mx = -1e30f;
    #pragma unroll
    for (int e = 0; e < E_; ++e) { l[e] = acc[e] + br[e]; mx = fmaxf(mx, l[e]); }
    float sum = 0.f;
    #pragma unroll
    for (int e = 0; e < E_; ++e) { p[e] = expf(l[e] - mx); sum += p[e]; }
    float inv = 1.f / sum;
    int bestE = 0; float bestP = -1.f; float ent = 0.f;
    #pragma unroll
    for (int e = 0; e < E_; ++e) {
      float pe = p[e] * inv;
      ent += pe * logf(pe + 1e-9f);
      if (pe > bestP) { bestP = pe; bestE = e; }
    }
    top[tok] = bestE; gate[tok] = bestP; entTok[tok] = ent;
    atomicAdd(&countsInt[bestE], 1);
  }
}

// ---------------- capacity assignment (single block) ----------------
__global__ __launch_bounds__(256) void slv_capacity(
    const int* __restrict__ top, int* __restrict__ slotTok, int* __restrict__ cntKept) {
  __shared__ unsigned char tops[NTOK];
  __shared__ int sb[256];
  int tid = threadIdx.x;
  for (int i = tid; i < NTOK; i += 256) tops[i] = (unsigned char)top[i];
  __syncthreads();
  int cnt[E_];
  #pragma unroll
  for (int e = 0; e < E_; ++e) cnt[e] = 0;
  int n0 = tid * 32;
  for (int i = 0; i < 32; ++i) {
    int v = tops[n0 + i];
    #pragma unroll
    for (int e = 0; e < E_; ++e) cnt[e] += (v == e) ? 1 : 0;
  }
  int base[E_];
  for (int e = 0; e < E_; ++e) {
    sb[tid] = cnt[e];
    __syncthreads();
    for (int off = 1; off < 256; off <<= 1) {
      int add = (tid >= off) ? sb[tid - off] : 0;
      __syncthreads();
      sb[tid] += add;
      __syncthreads();
    }
    base[e] = sb[tid] - cnt[e];      // exclusive prefix
    if (tid == 0) cntKept[e] = min(sb[255], CAP);
    __syncthreads();
  }
  for (int i = 0; i < 32; ++i) {
    int n = n0 + i;
    int v = tops[n];
    #pragma unroll
    for (int e = 0; e < E_; ++e) {
      if (v == e) {
        int r = base[e]++;
        if (r < CAP) slotTok[e * CAP + r] = n;
      }
    }
  }
}

// ---------------- gather tokens into expert slots (bf16) ----------------
__global__ __launch_bounds__(256) void slv_gather(
    const float* __restrict__ y, const int* __restrict__ slotTok,
    const int* __restrict__ cntKept, unsigned short* __restrict__ Xe) {
  int slot = blockIdx.x;             // 0..10239
  int e = slot / CAP, r = slot % CAP;
  int c4 = threadIdx.x * 4;
  ushort4 o;
  if (r < cntKept[e]) {
    int tok = slotTok[slot];
    float4 v = *(const float4*)(y + (size_t)tok * D_ + c4);
    o.x = f2bu(v.x); o.y = f2bu(v.y); o.z = f2bu(v.z); o.w = f2bu(v.w);
  } else {
    o.x = 0; o.y = 0; o.z = 0; o.w = 0;
  }
  *(ushort4*)(Xe + (size_t)slot * D_ + c4) = o;
}

// ---------------- fp32 -> bf16 transpose: out[c][r] = in[r][c] ----------------
__global__ __launch_bounds__(256) void slv_transpose(
    const float* __restrict__ in, bf16* __restrict__ out, int R, int C) {
  __shared__ float tile[64][65];
  size_t mat = (size_t)blockIdx.z * R * C;
  int c0 = blockIdx.x * 64, r0 = blockIdx.y * 64;
  int tid = threadIdx.x;
  #pragma unroll
  for (int j = 0; j < 16; ++j) {
    int idx = j * 256 + tid; int r = idx >> 6, c = idx & 63;
    tile[r][c] = in[mat + (size_t)(r0 + r) * C + c0 + c];
  }
  __syncthreads();
  #pragma unroll
  for (int j = 0; j < 16; ++j) {
    int idx = j * 256 + tid; int rr = idx & 63, cc = idx >> 6;
    out[mat + (size_t)(c0 + cc) * R + r0 + rr] = __float2bfloat16(tile[rr][cc]);
  }
}

// ---------------- shared MFMA GEMM core (BM=BN=128, BK=64, 4 waves) ----------------
__device__ __forceinline__ void gemm_core(
    const char* ga, const char* gb, int K, bf16* As, bf16* Bs,
    f32x4 (&acc)[4][4], int wave, int lane, int wr, int wc) {
  const int Krow = K * 2;
  for (int ks = 0; ks < K; ks += 64) {
    #pragma unroll
    for (int rnd = 0; rnd < 4; ++rnd) {
      int chunk = rnd * 4 + wave;               // wave-uniform
      int o = chunk * 1024 + lane * 16;         // byte offset in 16KB tile
      int row = o >> 7, col = o & 127;
      size_t gofs = (size_t)row * Krow + (size_t)ks * 2 + col;
      gll16(ga + gofs, (char*)As + chunk * 1024);
      gll16(gb + gofs, (char*)Bs + chunk * 1024);
    }
    __syncthreads();
    #pragma unroll
    for (int kk = 0; kk < 2; ++kk) {
      bf16x8 a[4], b[4];
      int koff = kk * 64 + ((lane >> 4) << 4);
      #pragma unroll
      for (int m = 0; m < 4; ++m)
        a[m] = *(const bf16x8*)((const char*)As + (wr * 64 + m * 16 + (lane & 15)) * 128 + koff);
      #pragma unroll
      for (int n = 0; n < 4; ++n)
        b[n] = *(const bf16x8*)((const char*)Bs + (wc * 64 + n * 16 + (lane & 15)) * 128 + koff);
      #pragma unroll
      for (int m = 0; m < 4; ++m)
        #pragma unroll
        for (int n = 0; n < 4; ++n)
          acc[m][n] = __builtin_amdgcn_mfma_f32_16x16x32_bf16(a[m], b[n], acc[m][n], 0, 0, 0);
    }
    __syncthreads();
  }
}

// ---------------- FFN1: He = gelu(Xe @ W1 + b1), bf16 out ----------------
__global__ __launch_bounds__(256) void slv_ffn1(
    const bf16* __restrict__ Xe, const bf16* __restrict__ W1t, const float* __restrict__ b1,
    const int* __restrict__ cntKept, unsigned short* __restrict__ He) {
  int e = blockIdx.z, mt = blockIdx.y, nt = blockIdx.x;   // (32,10,8)
  if (mt * 128 >= cntKept[e]) return;
  __shared__ __align__(16) bf16 As[128 * 64], Bs[128 * 64];
  int tid = threadIdx.x, wave = tid >> 6, lane = tid & 63;
  int wr = wave >> 1, wc = wave & 1;
  const char* ga = (const char*)(Xe + ((size_t)e * CAP + mt * 128) * D_);
  const char* gb = (const char*)(W1t + ((size_t)e * H_ + nt * 128) * D_);
  f32x4 acc[4][4] = {};
  gemm_core(ga, gb, D_, As, Bs, acc, wave, lane, wr, wc);
  size_t slot0 = (size_t)e * CAP + mt * 128;
  int colb = nt * 128 + wc * 64;
  #pragma unroll
  for (int m = 0; m < 4; ++m) {
    int trow0 = wr * 64 + m * 16 + ((lane >> 4) << 2);
    #pragma unroll
    for (int n = 0; n < 4; ++n) {
      int col = colb + n * 16 + (lane & 15);
      float bias = b1[e * H_ + col];
      #pragma unroll
      for (int r = 0; r < 4; ++r) {
        float x = acc[m][n][r] + bias;
        float t = tanhf(0.7978845608028654f * (x + 0.044715f * x * x * x));
        float gel = 0.5f * x * (1.f + t);
        He[(slot0 + trow0 + r) * (size_t)H_ + col] = f2bu(gel);
      }
    }
  }
}

// ---------------- FFN2: out[tok] = (He @ W2 + b2) * gate, scattered bf16 ----------------
__global__ __launch_bounds__(256) void slv_ffn2(
    const bf16* __restrict__ He, const bf16* __restrict__ W2t, const float* __restrict__ b2,
    const int* __restrict__ cntKept, const int* __restrict__ slotTok,
    const float* __restrict__ gate, unsigned short* __restrict__ outb) {
  int e = blockIdx.z, mt = blockIdx.y, nt = blockIdx.x;   // (8,10,8)
  int cnt = cntKept[e];
  if (mt * 128 >= cnt) return;
  __shared__ __align__(16) bf16 As[128 * 64], Bs[128 * 64];
  int tid = threadIdx.x, wave = tid >> 6, lane = tid & 63;
  int wr = wave >> 1, wc = wave & 1;
  const char* ga = (const char*)(He + ((size_t)e * CAP + mt * 128) * H_);
  const char* gb = (const char*)(W2t + ((size_t)e * D_ + nt * 128) * H_);
  f32x4 acc[4][4] = {};
  gemm_core(ga, gb, H_, As, Bs, acc, wave, lane, wr, wc);
  int colb = nt * 128 + wc * 64;
  #pragma unroll
  for (int m = 0; m < 4; ++m) {
    int trow0 = wr * 64 + m * 16 + ((lane >> 4) << 2);
    #pragma unroll
    for (int r = 0; r < 4; ++r) {
      int mrow = mt * 128 + trow0 + r;
      if (mrow < cnt) {
        int slot = e * CAP + mrow;
        int tok = slotTok[slot];
        float sc = gate[tok];
        #pragma unroll
        for (int n = 0; n < 4; ++n) {
          int col = colb + n * 16 + (lane & 15);
          float v = (acc[m][n][r] + b2[e * D_ + col]) * sc;
          outb[(size_t)tok * D_ + col] = f2bu(v);
        }
      }
    }
  }
}

// ---------------- head: logits = outb @ Wh + bh (fp32 out) ----------------
__global__ __launch_bounds__(256) void slv_head(
    const bf16* __restrict__ outb, const bf16* __restrict__ Wht, const float* __restrict__ bh,
    float* __restrict__ logits) {
  int nt = blockIdx.x, mt = blockIdx.y;    // (2,64)
  __shared__ __align__(16) bf16 As[128 * 64], Bs[128 * 64];
  int tid = threadIdx.x, wave = tid >> 6, lane = tid & 63;
  int wr = wave >> 1, wc = wave & 1;
  const char* ga = (const char*)(outb + (size_t)mt * 128 * D_);
  const char* gb = (const char*)(Wht + (size_t)nt * 128 * D_);
  f32x4 acc[4][4] = {};
  gemm_core(ga, gb, D_, As, Bs, acc, wave, lane, wr, wc);
  int colb = nt * 128 + wc * 64;
  #pragma unroll
  for (int m = 0; m < 4; ++m) {
    int trow0 = wr * 64 + m * 16 + ((lane >> 4) << 2);
    #pragma unroll
    for (int n = 0; n < 4; ++n) {
      int col = colb + n * 16 + (lane & 15);
      float bias = bh[col];
      #pragma unroll
      for (int r = 0; r < 4; ++r) {
        int row = mt * 128 + trow0 + r;
        logits[(size_t)row * VOCAB_ + col] = acc[m][n][r] + bias;
      }
    }
  }
}

// ---------------- finalize: entropy (deterministic) + counts ----------------
__global__ __launch_bounds__(256) void slv_finalize(
    const float* __restrict__ entTok, const int* __restrict__ countsInt,
    float* __restrict__ out) {
  __shared__ float red[256];
  int tid = threadIdx.x;
  float s = 0.f;
  for (int i = tid; i < NTOK; i += 256) s += entTok[i];
  red[tid] = s;
  __syncthreads();
  for (int off = 128; off; off >>= 1) {
    if (tid < off) red[tid] += red[tid + off];
    __syncthreads();
  }
  if (tid == 0) out[ENT_OFF] = -red[0] / (float)NTOK;
  if (tid < E_) out[CNT_OFF + tid] = (float)countsInt[tid];
}

extern "C" void kernel_launch(void* const* d_in, const int* in_sizes, int n_in,
                              void* d_out, int out_size, void* d_ws, size_t ws_size,
                              hipStream_t stream) {
  (void)in_sizes; (void)n_in; (void)out_size; (void)ws_size;
  const int*   byte_seq = (const int*)d_in[0];
  const float* emb = (const float*)d_in[1];
  const float* Wp  = (const float*)d_in[2];
  const float* bp  = (const float*)d_in[3];
  const float* Wg  = (const float*)d_in[4];
  const float* bg  = (const float*)d_in[5];
  const float* Wr  = (const float*)d_in[6];
  const float* br  = (const float*)d_in[7];
  const float* W1  = (const float*)d_in[8];
  const float* b1  = (const float*)d_in[9];
  const float* W2  = (const float*)d_in[10];
  const float* b2  = (const float*)d_in[11];
  const float* Wh  = (const float*)d_in[12];
  const float* bh  = (const float*)d_in[13];
  float* out = (float*)d_out;

  char* ws = (char*)d_ws;
  float* P        = (float*)(ws + OFF_P);
  float* G        = (float*)(ws + OFF_G);
  float* y        = (float*)(ws + OFF_Y);
  int*   top      = (int*)(ws + OFF_TOP);
  float* gate     = (float*)(ws + OFF_GATE);
  float* entTok   = (float*)(ws + OFF_ENT);
  int*   countsInt= (int*)(ws + OFF_CNT);
  int*   cntKept  = (int*)(ws + OFF_CKEPT);
  int*   slotTok  = (int*)(ws + OFF_SLOT);
  unsigned short* Xe  = (unsigned short*)(ws + OFF_XE);
  unsigned short* He  = (unsigned short*)(ws + OFF_HE);
  bf16*  Wt       = (bf16*)(ws + OFF_WT);
  bf16*  Wht      = (bf16*)(ws + OFF_WHT);
  unsigned short* outb = (unsigned short*)(ws + OFF_OUTB);

  hipMemsetAsync(countsInt, 0, E_ * sizeof(int), stream);
  hipMemsetAsync(outb, 0, (size_t)NTOK * D_ * 2, stream);

  slv_embproj<<<dim3(4, 16), 256, 0, stream>>>(emb, Wp, bp, Wg, bg, P, G);
  slv_scan<<<16, 256, 0, stream>>>(byte_seq, P, G, y, out + NS_OFF);
  slv_router<<<NTOK / 4, 256, 0, stream>>>(y, Wr, br, top, gate, entTok, countsInt);
  slv_capacity<<<1, 256, 0, stream>>>(top, slotTok, cntKept);
  slv_gather<<<E_ * CAP, 256, 0, stream>>>(y, slotTok, cntKept, Xe);

  // Wh^T (bf16), W1^T (bf16)
  slv_transpose<<<dim3(4, 16, 1), 256, 0, stream>>>(Wh, Wht, 1024, 256);
  slv_transpose<<<dim3(64, 16, 8), 256, 0, stream>>>(W1, Wt, 1024, 4096);
  slv_ffn1<<<dim3(32, 10, 8), 256, 0, stream>>>((const bf16*)Xe, Wt, b1, cntKept, He);
  // reuse Wt for W2^T
  slv_transpose<<<dim3(16, 64, 8), 256, 0, stream>>>(W2, Wt, 4096, 1024);
  slv_ffn2<<<dim3(8, 10, 8), 256, 0, stream>>>((const bf16*)He, Wt, b2, cntKept, slotTok, gate, outb);
  slv_head<<<dim3(2, 64), 256, 0, stream>>>((const bf16*)outb, Wht, bh, out + LOGITS_OFF);
  slv_finalize<<<1, 256, 0, stream>>>(entTok, countsInt, out);
}

// Round 2
// 695.800 us; speedup vs baseline: 1.9563x; 1.9563x over previous
//
#include <hip/hip_runtime.h>
#include <hip/hip_bf16.h>
#include <cstdint>
#include <cstddef>

#define AS1 __attribute__((address_space(1)))
#define AS3 __attribute__((address_space(3)))

typedef __hip_bfloat16 bf16;
typedef float f32x4 __attribute__((ext_vector_type(4)));
typedef short bf16x8 __attribute__((ext_vector_type(8)));

#define B_     4
#define T_     2048
#define D_     1024
#define E_     8
#define H_     4096
#define NTOK   8192
#define CAP    1280
#define VOCAB_ 256

// ---- workspace layout (bytes) ----
static constexpr size_t OFF_P     = 0;                 // 256*1024*4   = 1 MB
static constexpr size_t OFF_G     = 1048576;           // 1 MB
static constexpr size_t OFF_Y     = 2097152;           // 8192*1024*4  = 32 MB
static constexpr size_t OFF_TOP   = 35651584;          // 8192*4
static constexpr size_t OFF_GATE  = 35684352;          // 8192*4
static constexpr size_t OFF_ENT   = 35717120;          // 8192*4
static constexpr size_t OFF_CNT   = 35749888;          // 8*4 (pad 256)
static constexpr size_t OFF_CKEPT = 35750144;          // 8*4 (pad 256)
static constexpr size_t OFF_SLOT  = 35750400;          // 10240*4
static constexpr size_t OFF_XE    = 35791360;          // 10240*1024*2 = 20 MB
static constexpr size_t OFF_HE    = 56762880;          // 10240*4096*2 = 80 MB (also embproj partials early)
static constexpr size_t OFF_WT    = 140648960;         // 64 MB (W1t then W2t)
static constexpr size_t OFF_WHT   = 207757824;         // 256*1024*2
static constexpr size_t OFF_OUTB  = 208282112;         // 8192*1024*2  = 16 MB

// d_out layout (floats)
#define LOGITS_OFF 0
#define NS_OFF     2097152
#define ENT_OFF    2101248
#define CNT_OFF    2101249

__device__ __forceinline__ void gll16(const void* g, void* l) {
  __builtin_amdgcn_global_load_lds((AS1 const void*)g, (AS3 void*)l, 16, 0, 0);
}
__device__ __forceinline__ unsigned short f2bu(float f) {
  bf16 h = __float2bfloat16(f);
  return __builtin_bit_cast(unsigned short, h);
}
// tanh(z) = 1 - 2/(exp(2z)+1); v_exp+v_rcp, ~1e-6 rel err (safe: router margins >> 1e-4)
__device__ __forceinline__ float fast_tanh(float z) {
  float e2 = __expf(z + z);
  return fmaf(-2.f, __builtin_amdgcn_rcpf(e2 + 1.f), 1.f);
}

// ---------------- embproj split-K partial GEMM ----------------
// grid (32 rowblocks of 8, 8 kchunks of 128), 256 thr; thread = 8 rows x 4 cols.
__global__ __launch_bounds__(256) void slv_embproj_part(
    const float* __restrict__ emb, const float* __restrict__ Wp,
    const float* __restrict__ Wg,
    float* __restrict__ Ppart, float* __restrict__ Gpart) {
  __shared__ float embT[128][9];   // pad 9: 4-way max conflict on transpose write
  int rb = blockIdx.x, kc = blockIdx.y;
  int r0 = rb * 8, k0 = kc * 128;
  int tid = threadIdx.x;
  int c = tid * 4;
  {
    int i4 = tid * 4;
    int r = i4 >> 7, kb = i4 & 127;       // coalesced float4 read of emb row slice
    f32x4 v = *reinterpret_cast<const f32x4*>(emb + (size_t)(r0 + r) * D_ + k0 + kb);
    embT[kb + 0][r] = v.x; embT[kb + 1][r] = v.y;
    embT[kb + 2][r] = v.z; embT[kb + 3][r] = v.w;
  }
  __syncthreads();
  f32x4 aP[8] = {}, aG[8] = {};
  #pragma unroll 4
  for (int kk = 0; kk < 128; ++kk) {
    f32x4 wp = *reinterpret_cast<const f32x4*>(Wp + (size_t)(k0 + kk) * D_ + c);
    f32x4 wg = *reinterpret_cast<const f32x4*>(Wg + (size_t)(k0 + kk) * D_ + c);
    #pragma unroll
    for (int r = 0; r < 8; ++r) {
      float e = embT[kk][r];                // broadcast read
      aP[r] += e * wp;
      aG[r] += e * wg;
    }
  }
  #pragma unroll
  for (int r = 0; r < 8; ++r) {
    size_t o = ((size_t)kc * 256 + r0 + r) * D_ + c;
    *reinterpret_cast<f32x4*>(Ppart + o) = aP[r];
    *reinterpret_cast<f32x4*>(Gpart + o) = aG[r];
  }
}

// reduce 8 k-partials, add bias, sigmoid for G
__global__ __launch_bounds__(256) void slv_embproj_reduce(
    const float* __restrict__ Ppart, const float* __restrict__ Gpart,
    const float* __restrict__ bp, const float* __restrict__ bg,
    float* __restrict__ P, float* __restrict__ G) {
  int i = blockIdx.x * 256 + threadIdx.x;   // 65536 threads, float4 each
  int r = i >> 8;
  int c = (i & 255) * 4;
  f32x4 sp = {}, sg = {};
  #pragma unroll
  for (int kc = 0; kc < 8; ++kc) {
    size_t o = ((size_t)kc * 256 + r) * D_ + c;
    sp += *reinterpret_cast<const f32x4*>(Ppart + o);
    sg += *reinterpret_cast<const f32x4*>(Gpart + o);
  }
  sp += *reinterpret_cast<const f32x4*>(bp + c);
  sg += *reinterpret_cast<const f32x4*>(bg + c);
  f32x4 g;
  g.x = 1.f / (1.f + __expf(-sg.x));
  g.y = 1.f / (1.f + __expf(-sg.y));
  g.z = 1.f / (1.f + __expf(-sg.z));
  g.w = 1.f / (1.f + __expf(-sg.w));
  *reinterpret_cast<f32x4*>(P + (size_t)r * D_ + c) = sp;
  *reinterpret_cast<f32x4*>(G + (size_t)r * D_ + c) = g;
}

// ---------------- SSM scan ----------------
// 4096 channels (b,d), each serial over T. y[b,t,d] = G*s ; next_state -> d_out.
__global__ __launch_bounds__(256) void slv_scan(
    const int* __restrict__ bytes, const float* __restrict__ P, const float* __restrict__ G,
    float* __restrict__ y, float* __restrict__ ns) {
  int b = blockIdx.x >> 2;
  int d = (blockIdx.x & 3) * 256 + threadIdx.x;
  __shared__ int bl[T_];
  for (int i = threadIdx.x; i < T_; i += 256) bl[i] = bytes[b * T_ + i];
  __syncthreads();
  float s = 0.f;
  for (int t = 0; t < T_; ++t) {
    int by = bl[t];
    float p = P[by * D_ + d];
    float g = G[by * D_ + d];
    s = fast_tanh(p + s);
    y[((size_t)(b * T_ + t)) * D_ + d] = g * s;
  }
  ns[b * D_ + d] = s;
}

// ---------------- router ----------------
// one wave per token: logits = y@Wr+br, softmax, argmax(first-max), gate, entropy.
__global__ __launch_bounds__(256) void slv_router(
    const float* __restrict__ y, const float* __restrict__ Wr, const float* __restrict__ br,
    int* __restrict__ top, float* __restrict__ gate, float* __restrict__ entTok,
    int* __restrict__ countsInt) {
  int wave = threadIdx.x >> 6, lane = threadIdx.x & 63;
  int tok = blockIdx.x * 4 + wave;
  const float* yr = y + (size_t)tok * D_;
  float acc[E_];
  #pragma unroll
  for (int e = 0; e < E_; ++e) acc[e] = 0.f;
  for (int i = 0; i < 16; ++i) {
    int d = i * 64 + lane;
    float v = yr[d];
    const float4* w = (const float4*)(Wr + d * E_);
    float4 w0 = w[0], w1 = w[1];
    acc[0] = fmaf(v, w0.x, acc[0]); acc[1] = fmaf(v, w0.y, acc[1]);
    acc[2] = fmaf(v, w0.z, acc[2]); acc[3] = fmaf(v, w0.w, acc[3]);
    acc[4] = fmaf(v, w1.x, acc[4]); acc[5] = fmaf(v, w1.y, acc[5]);
    acc[6] = fmaf(v, w1.z, acc[6]); acc[7] = fmaf(v, w1.w, acc[7]);
  }
  #pragma unroll
  for (int off = 32; off; off >>= 1)
    #pragma unroll
    for (int e = 0; e < E_; ++e) acc[e] += __shfl_xor(acc[e], off);
  if (lane == 0) {
    float l[E_], p[E_];
    float mx = -1e30f;
    #pragma unroll
    for (int e = 0; e < E_; ++e) { l[e] = acc[e] + br[e]; mx = fmaxf(mx, l[e]); }
    float sum = 0.f;
    #pragma unroll
    for (int e = 0; e < E_; ++e) { p[e] = expf(l[e] - mx); sum += p[e]; }
    float inv = 1.f / sum;
    int bestE = 0; float bestP = -1.f; float ent = 0.f;
    #pragma unroll
    for (int e = 0; e < E_; ++e) {
      float pe = p[e] * inv;
      ent += pe * logf(pe + 1e-9f);
      if (pe > bestP) { bestP = pe; bestE = e; }
    }
    top[tok] = bestE; gate[tok] = bestP; entTok[tok] = ent;
    atomicAdd(&countsInt[bestE], 1);
  }
}

// ---------------- capacity assignment (single block) ----------------
__global__ __launch_bounds__(256) void slv_capacity(
    const int* __restrict__ top, int* __restrict__ slotTok, int* __restrict__ cntKept) {
  __shared__ unsigned char tops[NTOK];
  __shared__ int sb[256];
  int tid = threadIdx.x;
  for (int i = tid; i < NTOK; i += 256) tops[i] = (unsigned char)top[i];
  __syncthreads();
  int cnt[E_];
  #pragma unroll
  for (int e = 0; e < E_; ++e) cnt[e] = 0;
  int n0 = tid * 32;
  for (int i = 0; i < 32; ++i) {
    int v = tops[n0 + i];
    #pragma unroll
    for (int e = 0; e < E_; ++e) cnt[e] += (v == e) ? 1 : 0;
  }
  int base[E_];
  for (int e = 0; e < E_; ++e) {
    sb[tid] = cnt[e];
    __syncthreads();
    for (int off = 1; off < 256; off <<= 1) {
      int add = (tid >= off) ? sb[tid - off] : 0;
      __syncthreads();
      sb[tid] += add;
      __syncthreads();
    }
    base[e] = sb[tid] - cnt[e];      // exclusive prefix
    if (tid == 0) cntKept[e] = min(sb[255], CAP);
    __syncthreads();
  }
  for (int i = 0; i < 32; ++i) {
    int n = n0 + i;
    int v = tops[n];
    #pragma unroll
    for (int e = 0; e < E_; ++e) {
      if (v == e) {
        int r = base[e]++;
        if (r < CAP) slotTok[e * CAP + r] = n;
      }
    }
  }
}

// ---------------- gather tokens into expert slots (bf16) ----------------
__global__ __launch_bounds__(256) void slv_gather(
    const float* __restrict__ y, const int* __restrict__ slotTok,
    const int* __restrict__ cntKept, unsigned short* __restrict__ Xe) {
  int slot = blockIdx.x;             // 0..10239
  int e = slot / CAP, r = slot % CAP;
  int c4 = threadIdx.x * 4;
  ushort4 o;
  if (r < cntKept[e]) {
    int tok = slotTok[slot];
    float4 v = *(const float4*)(y + (size_t)tok * D_ + c4);
    o.x = f2bu(v.x); o.y = f2bu(v.y); o.z = f2bu(v.z); o.w = f2bu(v.w);
  } else {
    o.x = 0; o.y = 0; o.z = 0; o.w = 0;
  }
  *(ushort4*)(Xe + (size_t)slot * D_ + c4) = o;
}

// ---------------- fp32 -> bf16 transpose: out[c][r] = in[r][c] ----------------
__global__ __launch_bounds__(256) void slv_transpose(
    const float* __restrict__ in, bf16* __restrict__ out, int R, int C) {
  __shared__ float tile[64][65];
  size_t mat = (size_t)blockIdx.z * R * C;
  int c0 = blockIdx.x * 64, r0 = blockIdx.y * 64;
  int tid = threadIdx.x;
  #pragma unroll
  for (int j = 0; j < 16; ++j) {
    int idx = j * 256 + tid; int r = idx >> 6, c = idx & 63;
    tile[r][c] = in[mat + (size_t)(r0 + r) * C + c0 + c];
  }
  __syncthreads();
  #pragma unroll
  for (int j = 0; j < 16; ++j) {
    int idx = j * 256 + tid; int rr = idx & 63, cc = idx >> 6;
    out[mat + (size_t)(c0 + cc) * R + r0 + rr] = __float2bfloat16(tile[rr][cc]);
  }
}

// ---------------- shared MFMA GEMM core (BM=BN=128, BK=64, 4 waves) ----------------
__device__ __forceinline__ void gemm_core(
    const char* ga, const char* gb, int K, bf16* As, bf16* Bs,
    f32x4 (&acc)[4][4], int wave, int lane, int wr, int wc) {
  const int Krow = K * 2;
  for (int ks = 0; ks < K; ks += 64) {
    #pragma unroll
    for (int rnd = 0; rnd < 4; ++rnd) {
      int chunk = rnd * 4 + wave;               // wave-uniform
      int o = chunk * 1024 + lane * 16;         // byte offset in 16KB tile
      int row = o >> 7, col = o & 127;
      size_t gofs = (size_t)row * Krow + (size_t)ks * 2 + col;
      gll16(ga + gofs, (char*)As + chunk * 1024);
      gll16(gb + gofs, (char*)Bs + chunk * 1024);
    }
    __syncthreads();
    #pragma unroll
    for (int kk = 0; kk < 2; ++kk) {
      bf16x8 a[4], b[4];
      int koff = kk * 64 + ((lane >> 4) << 4);
      #pragma unroll
      for (int m = 0; m < 4; ++m)
        a[m] = *(const bf16x8*)((const char*)As + (wr * 64 + m * 16 + (lane & 15)) * 128 + koff);
      #pragma unroll
      for (int n = 0; n < 4; ++n)
        b[n] = *(const bf16x8*)((const char*)Bs + (wc * 64 + n * 16 + (lane & 15)) * 128 + koff);
      #pragma unroll
      for (int m = 0; m < 4; ++m)
        #pragma unroll
        for (int n = 0; n < 4; ++n)
          acc[m][n] = __builtin_amdgcn_mfma_f32_16x16x32_bf16(a[m], b[n], acc[m][n], 0, 0, 0);
    }
    __syncthreads();
  }
}

// ---------------- FFN1: He = gelu(Xe @ W1 + b1), bf16 out ----------------
__global__ __launch_bounds__(256) void slv_ffn1(
    const bf16* __restrict__ Xe, const bf16* __restrict__ W1t, const float* __restrict__ b1,
    const int* __restrict__ cntKept, unsigned short* __restrict__ He) {
  int e = blockIdx.z, mt = blockIdx.y, nt = blockIdx.x;   // (32,10,8)
  if (mt * 128 >= cntKept[e]) return;
  __shared__ __align__(16) bf16 As[128 * 64], Bs[128 * 64];
  int tid = threadIdx.x, wave = tid >> 6, lane = tid & 63;
  int wr = wave >> 1, wc = wave & 1;
  const char* ga = (const char*)(Xe + ((size_t)e * CAP + mt * 128) * D_);
  const char* gb = (const char*)(W1t + ((size_t)e * H_ + nt * 128) * D_);
  f32x4 acc[4][4] = {};
  gemm_core(ga, gb, D_, As, Bs, acc, wave, lane, wr, wc);
  size_t slot0 = (size_t)e * CAP + mt * 128;
  int colb = nt * 128 + wc * 64;
  #pragma unroll
  for (int m = 0; m < 4; ++m) {
    int trow0 = wr * 64 + m * 16 + ((lane >> 4) << 2);
    #pragma unroll
    for (int n = 0; n < 4; ++n) {
      int col = colb + n * 16 + (lane & 15);
      float bias = b1[e * H_ + col];
      #pragma unroll
      for (int r = 0; r < 4; ++r) {
        float x = acc[m][n][r] + bias;
        float t = fast_tanh(0.7978845608028654f * (x + 0.044715f * x * x * x));
        float gel = 0.5f * x * (1.f + t);
        He[(slot0 + trow0 + r) * (size_t)H_ + col] = f2bu(gel);
      }
    }
  }
}

// ---------------- FFN2: out[tok] = (He @ W2 + b2) * gate, scattered bf16 ----------------
__global__ __launch_bounds__(256) void slv_ffn2(
    const bf16* __restrict__ He, const bf16* __restrict__ W2t, const float* __restrict__ b2,
    const int* __restrict__ cntKept, const int* __restrict__ slotTok,
    const float* __restrict__ gate, unsigned short* __restrict__ outb) {
  int e = blockIdx.z, mt = blockIdx.y, nt = blockIdx.x;   // (8,10,8)
  int cnt = cntKept[e];
  if (mt * 128 >= cnt) return;
  __shared__ __align__(16) bf16 As[128 * 64], Bs[128 * 64];
  int tid = threadIdx.x, wave = tid >> 6, lane = tid & 63;
  int wr = wave >> 1, wc = wave & 1;
  const char* ga = (const char*)(He + ((size_t)e * CAP + mt * 128) * H_);
  const char* gb = (const char*)(W2t + ((size_t)e * D_ + nt * 128) * H_);
  f32x4 acc[4][4] = {};
  gemm_core(ga, gb, H_, As, Bs, acc, wave, lane, wr, wc);
  int colb = nt * 128 + wc * 64;
  #pragma unroll
  for (int m = 0; m < 4; ++m) {
    int trow0 = wr * 64 + m * 16 + ((lane >> 4) << 2);
    #pragma unroll
    for (int r = 0; r < 4; ++r) {
      int mrow = mt * 128 + trow0 + r;
      if (mrow < cnt) {
        int slot = e * CAP + mrow;
        int tok = slotTok[slot];
        float sc = gate[tok];
        #pragma unroll
        for (int n = 0; n < 4; ++n) {
          int col = colb + n * 16 + (lane & 15);
          float v = (acc[m][n][r] + b2[e * D_ + col]) * sc;
          outb[(size_t)tok * D_ + col] = f2bu(v);
        }
      }
    }
  }
}

// ---------------- head: logits = outb @ Wh + bh (fp32 out) ----------------
__global__ __launch_bounds__(256) void slv_head(
    const bf16* __restrict__ outb, const bf16* __restrict__ Wht, const float* __restrict__ bh,
    float* __restrict__ logits) {
  int nt = blockIdx.x, mt = blockIdx.y;    // (2,64)
  __shared__ __align__(16) bf16 As[128 * 64], Bs[128 * 64];
  int tid = threadIdx.x, wave = tid >> 6, lane = tid & 63;
  int wr = wave >> 1, wc = wave & 1;
  const char* ga = (const char*)(outb + (size_t)mt * 128 * D_);
  const char* gb = (const char*)(Wht + (size_t)nt * 128 * D_);
  f32x4 acc[4][4] = {};
  gemm_core(ga, gb, D_, As, Bs, acc, wave, lane, wr, wc);
  int colb = nt * 128 + wc * 64;
  #pragma unroll
  for (int m = 0; m < 4; ++m) {
    int trow0 = wr * 64 + m * 16 + ((lane >> 4) << 2);
    #pragma unroll
    for (int n = 0; n < 4; ++n) {
      int col = colb + n * 16 + (lane & 15);
      float bias = bh[col];
      #pragma unroll
      for (int r = 0; r < 4; ++r) {
        int row = mt * 128 + trow0 + r;
        logits[(size_t)row * VOCAB_ + col] = acc[m][n][r] + bias;
      }
    }
  }
}

// ---------------- finalize: entropy (deterministic) + counts ----------------
__global__ __launch_bounds__(256) void slv_finalize(
    const float* __restrict__ entTok, const int* __restrict__ countsInt,
    float* __restrict__ out) {
  __shared__ float red[256];
  int tid = threadIdx.x;
  float s = 0.f;
  for (int i = tid; i < NTOK; i += 256) s += entTok[i];
  red[tid] = s;
  __syncthreads();
  for (int off = 128; off; off >>= 1) {
    if (tid < off) red[tid] += red[tid + off];
    __syncthreads();
  }
  if (tid == 0) out[ENT_OFF] = -red[0] / (float)NTOK;
  if (tid < E_) out[CNT_OFF + tid] = (float)countsInt[tid];
}

extern "C" void kernel_launch(void* const* d_in, const int* in_sizes, int n_in,
                              void* d_out, int out_size, void* d_ws, size_t ws_size,
                              hipStream_t stream) {
  (void)in_sizes; (void)n_in; (void)out_size; (void)ws_size;
  const int*   byte_seq = (const int*)d_in[0];
  const float* emb = (const float*)d_in[1];
  const float* Wp  = (const float*)d_in[2];
  const float* bp  = (const float*)d_in[3];
  const float* Wg  = (const float*)d_in[4];
  const float* bg  = (const float*)d_in[5];
  const float* Wr  = (const float*)d_in[6];
  const float* br  = (const float*)d_in[7];
  const float* W1  = (const float*)d_in[8];
  const float* b1  = (const float*)d_in[9];
  const float* W2  = (const float*)d_in[10];
  const float* b2  = (const float*)d_in[11];
  const float* Wh  = (const float*)d_in[12];
  const float* bh  = (const float*)d_in[13];
  float* out = (float*)d_out;

  char* ws = (char*)d_ws;
  float* P        = (float*)(ws + OFF_P);
  float* G        = (float*)(ws + OFF_G);
  float* y        = (float*)(ws + OFF_Y);
  int*   top      = (int*)(ws + OFF_TOP);
  float* gate     = (float*)(ws + OFF_GATE);
  float* entTok   = (float*)(ws + OFF_ENT);
  int*   countsInt= (int*)(ws + OFF_CNT);
  int*   cntKept  = (int*)(ws + OFF_CKEPT);
  int*   slotTok  = (int*)(ws + OFF_SLOT);
  unsigned short* Xe  = (unsigned short*)(ws + OFF_XE);
  unsigned short* He  = (unsigned short*)(ws + OFF_HE);
  bf16*  Wt       = (bf16*)(ws + OFF_WT);
  bf16*  Wht      = (bf16*)(ws + OFF_WHT);
  unsigned short* outb = (unsigned short*)(ws + OFF_OUTB);
  // embproj split-K partials live in the (not-yet-used) He region
  float* Ppart    = (float*)(ws + OFF_HE);
  float* Gpart    = (float*)(ws + OFF_HE + 8388608);

  hipMemsetAsync(countsInt, 0, E_ * sizeof(int), stream);
  hipMemsetAsync(outb, 0, (size_t)NTOK * D_ * 2, stream);

  slv_embproj_part<<<dim3(32, 8), 256, 0, stream>>>(emb, Wp, Wg, Ppart, Gpart);
  slv_embproj_reduce<<<256, 256, 0, stream>>>(Ppart, Gpart, bp, bg, P, G);
  slv_scan<<<16, 256, 0, stream>>>(byte_seq, P, G, y, out + NS_OFF);
  slv_router<<<NTOK / 4, 256, 0, stream>>>(y, Wr, br, top, gate, entTok, countsInt);
  slv_capacity<<<1, 256, 0, stream>>>(top, slotTok, cntKept);
  slv_gather<<<E_ * CAP, 256, 0, stream>>>(y, slotTok, cntKept, Xe);

  // Wh^T (bf16), W1^T (bf16)
  slv_transpose<<<dim3(4, 16, 1), 256, 0, stream>>>(Wh, Wht, 1024, 256);
  slv_transpose<<<dim3(64, 16, 8), 256, 0, stream>>>(W1, Wt, 1024, 4096);
  slv_ffn1<<<dim3(32, 10, 8), 256, 0, stream>>>((const bf16*)Xe, Wt, b1, cntKept, He);
  // reuse Wt for W2^T
  slv_transpose<<<dim3(16, 64, 8), 256, 0, stream>>>(W2, Wt, 4096, 1024);
  slv_ffn2<<<dim3(8, 10, 8), 256, 0, stream>>>((const bf16*)He, Wt, b2, cntKept, slotTok, gate, outb);
  slv_head<<<dim3(2, 64), 256, 0, stream>>>((const bf16*)outb, Wht, bh, out + LOGITS_OFF);
  slv_finalize<<<1, 256, 0, stream>>>(entTok, countsInt, out);
}